// Round 3
// baseline (482.730 us; speedup 1.0000x reference)
//
#include <hip/hip_runtime.h>
#include <cstdint>
#include <cstddef>
#include <type_traits>

using f32x4 = __attribute__((ext_vector_type(4))) float;
using s16x8 = __attribute__((ext_vector_type(8))) short;

__device__ __forceinline__ ushort f2bf(float x) {
    uint32_t u = __builtin_bit_cast(uint32_t, x);
    u += 0x7fffu + ((u >> 16) & 1u);          // round-to-nearest-even
    return (ushort)(u >> 16);
}
__device__ __forceinline__ float bflo(uint32_t u) { return __builtin_bit_cast(float, u << 16); }
__device__ __forceinline__ float bfhi(uint32_t u) { return __builtin_bit_cast(float, u & 0xffff0000u); }

#define GLOAD_LDS16(g, l)                                                                  \
    __builtin_amdgcn_global_load_lds((const __attribute__((address_space(1))) void*)(g),  \
                                     (__attribute__((address_space(3))) void*)(l), 16, 0, 0)

// ---------------------------------------------------------------- CSR build
// fused: per-wave edge-weight sum -> atomic, plus degree count
__global__ void degree_kernel(const int* __restrict__ ei, const float* __restrict__ ew,
                              int* __restrict__ deg, float* __restrict__ ew_sum, int E, int N) {
    int e = blockIdx.x * blockDim.x + threadIdx.x;
    float s = (e < E) ? ew[e] : 0.f;
    for (int o = 32; o; o >>= 1) s += __shfl_xor(s, o, 64);
    if ((threadIdx.x & 63) == 0) atomicAdd(ew_sum, s);
    if (e >= E + N) return;
    int d = (e < E) ? ei[E + e] : (e - E);
    atomicAdd(&deg[d], 1);
}

__global__ void scan_partial(const int* __restrict__ deg, int n, int* __restrict__ bsum) {
    __shared__ int lds[256];
    int t = threadIdx.x;
    int base = blockIdx.x * 1024 + t * 4;
    int s = 0;
#pragma unroll
    for (int j = 0; j < 4; ++j) if (base + j < n) s += deg[base + j];
    lds[t] = s; __syncthreads();
    for (int o = 128; o; o >>= 1) { if (t < o) lds[t] += lds[t + o]; __syncthreads(); }
    if (t == 0) bsum[blockIdx.x] = lds[0];
}

__global__ void scan_block(const int* __restrict__ bsum, int nb, int* __restrict__ boff,
                           int* __restrict__ row_start, int n, int total) {
    __shared__ int lds[256];
    int t = threadIdx.x;
    int v = (t < nb) ? bsum[t] : 0;
    lds[t] = v; __syncthreads();
    for (int o = 1; o < 256; o <<= 1) {
        int y = (t >= o) ? lds[t - o] : 0;
        __syncthreads();
        lds[t] += y;
        __syncthreads();
    }
    if (t < nb) boff[t] = lds[t] - v;   // exclusive
    if (t == 0) row_start[n] = total;
}

__global__ void scan_final(const int* __restrict__ deg, int n, const int* __restrict__ boff,
                           int* __restrict__ row_start) {
    __shared__ int lds[256];
    int t = threadIdx.x;
    int base = blockIdx.x * 1024 + t * 4;
    int d[4], loc[4], s = 0;
#pragma unroll
    for (int j = 0; j < 4; ++j) d[j] = (base + j < n) ? deg[base + j] : 0;
#pragma unroll
    for (int j = 0; j < 4; ++j) { loc[j] = s; s += d[j]; }
    lds[t] = s; __syncthreads();
    for (int o = 1; o < 256; o <<= 1) {
        int y = (t >= o) ? lds[t - o] : 0;
        __syncthreads();
        lds[t] += y;
        __syncthreads();
    }
    int texcl = lds[t] - s + boff[blockIdx.x];
#pragma unroll
    for (int j = 0; j < 4; ++j) if (base + j < n) row_start[base + j] = texcl + loc[j];
}

__global__ void scatter_kernel(const int* __restrict__ ei, const float* __restrict__ ew,
                               const float* __restrict__ ew_sum, const int* __restrict__ row_start,
                               int* __restrict__ cursor, int* __restrict__ csr_src,
                               float* __restrict__ csr_ea, int E, int N) {
    int e = blockIdx.x * blockDim.x + threadIdx.x;
    if (e >= E + N) return;
    int s, d; float w;
    if (e < E) { s = ei[e]; d = ei[E + e]; w = ew[e]; }
    else       { s = d = e - E;            w = ew_sum[0] / (float)E; }
    int pos = row_start[d] + atomicAdd(&cursor[d], 1);
    csr_src[pos] = s;
    csr_ea[pos] = w;
}

// ---------------------------------------------------------------- prep: emb->bf16 + WT builds (one launch)
__global__ void prep_kernel(const float* __restrict__ emb, ushort* __restrict__ embb, int n4,
                            const float* __restrict__ Wl0, const float* __restrict__ Wr0,
                            ushort* __restrict__ WT0,
                            const float* __restrict__ Wl1, const float* __restrict__ Wr1,
                            ushort* __restrict__ WT1) {
    int i = blockIdx.x * 256 + threadIdx.x;
    if (i < n4) {
        float4 v = ((const float4*)emb)[i];
        ushort4 o;
        o.x = f2bf(v.x); o.y = f2bf(v.y); o.z = f2bf(v.z); o.w = f2bf(v.w);
        ((ushort4*)embb)[i] = o;
        return;
    }
    int j = i - n4;
    if (j < 128 * 256) {
        int k = j >> 8, c = j & 255;
        float v = (c < 128) ? Wl0[k * 128 + c] : Wr0[k * 128 + (c - 128)];
        WT0[(size_t)c * 128 + k] = f2bf(v);
        return;
    }
    j -= 128 * 256;
    if (j < 128 * 512) {
        int k = j >> 9, c = j & 511;
        float v = (c < 256) ? Wl1[k * 256 + c] : Wr1[k * 256 + (c - 256)];
        WT1[(size_t)c * 128 + k] = f2bf(v);
    }
}

// ---------------------------------------------------------------- persistent col-panel MFMA GEMM
// Y[:, panel*128 .. +127] = X[n,128] @ WT^T + bias, written bf16 into xl/xr half.
// B panel staged once; A tiles double-buffered via global_load_lds (16B) with
// XOR swizzle: LDS linear dest + pre-swizzled global source + swizzled ds_read.
__global__ __launch_bounds__(512) void mfma_linear2(const ushort* __restrict__ Xb,
                                                    const ushort* __restrict__ WT,
                                                    const float* __restrict__ bl,
                                                    const float* __restrict__ br,
                                                    ushort* __restrict__ xl,
                                                    ushort* __restrict__ xr,
                                                    int n, int HALF) {
    __shared__ ushort sB[128 * 128];
    __shared__ ushort sA[2][128 * 128];
    const int tid = threadIdx.x;
    const int c0 = blockIdx.x * 128;
    const int ntiles = (n + 127) >> 7;

    // stage B panel (rows c0..c0+127 of WT)
    {
        const ushort* src = WT + (size_t)c0 * 128;
#pragma unroll
        for (int it = 0; it < 4; ++it) {
            int f = tid + it * 512;
            int row = f >> 4, ch = f & 15;
            const ushort* g = src + (size_t)row * 128 + ((ch ^ (row & 7)) << 3);
            ushort* lp = sB + (((size_t)it * 512 + (tid & ~63)) << 3);
            GLOAD_LDS16(g, lp);
        }
    }

    auto stageA = [&](ushort* dstLds, int rt) {
        int r0 = rt << 7;
#pragma unroll
        for (int it = 0; it < 4; ++it) {
            int f = tid + it * 512;
            int row = f >> 4, ch = f & 15;
            int gr = r0 + row; gr = gr < n ? gr : n - 1;
            const ushort* g = Xb + (size_t)gr * 128 + ((ch ^ (row & 7)) << 3);
            ushort* lp = dstLds + (((size_t)it * 512 + (tid & ~63)) << 3);
            GLOAD_LDS16(g, lp);
        }
    };

    const int w = tid >> 6, l = tid & 63, lr = l & 15, lg = l >> 4;
    const bool left = c0 < HALF;
    const float* bias = left ? bl : br;
    ushort* dst = left ? xl : xr;
    const int cb = left ? c0 : c0 - HALF;
    float bv[8];
#pragma unroll
    for (int tn = 0; tn < 8; ++tn) bv[tn] = bias[cb + tn * 16 + lr];

    int rt = blockIdx.y;
    stageA(sA[0], rt);
    __syncthreads();

    int cur = 0;
    const int arow = w * 16 + lr;
    while (true) {
        int nx = rt + gridDim.y;
        if (nx < ntiles) stageA(sA[cur ^ 1], nx);

        f32x4 acc[8] = {};
        const ushort* sAc = sA[cur];
#pragma unroll
        for (int kk = 0; kk < 4; ++kk) {
            int ach = (kk * 4 + lg) ^ (arow & 7);
            s16x8 a = *(const s16x8*)&sAc[arow * 128 + (ach << 3)];
#pragma unroll
            for (int tn = 0; tn < 8; ++tn) {
                int brow = tn * 16 + lr;
                int bch = (kk * 4 + lg) ^ (brow & 7);
                s16x8 b = *(const s16x8*)&sB[brow * 128 + (bch << 3)];
                acc[tn] = __builtin_amdgcn_mfma_f32_16x16x32_bf16(a, b, acc[tn], 0, 0, 0);
            }
        }
        int rbase = (rt << 7) + w * 16 + lg * 4;
#pragma unroll
        for (int tn = 0; tn < 8; ++tn) {
            int colh = cb + tn * 16 + lr;
#pragma unroll
            for (int r = 0; r < 4; ++r) {
                int row = rbase + r;
                if (row < n) dst[(size_t)row * HALF + colh] = f2bf(acc[tn][r] + bv[tn]);
            }
        }
        if (nx >= ntiles) break;
        __syncthreads();
        cur ^= 1; rt = nx;
    }
}

// ---------------------------------------------------------------- GATv2 aggregation
// one wave per dst node; chunk-of-8 prefetched gathers, ping-pong buffered;
// one softmax rescale per chunk, tail masked via p=-inf (exp->0, exact no-op).
template <int H, int C>
__global__ __launch_bounds__(256) void gat_agg(const ushort* __restrict__ xl, const ushort* __restrict__ xr,
                                               const int* __restrict__ row_start,
                                               const int* __restrict__ csr_src,
                                               const float* __restrict__ csr_ea,
                                               const float* __restrict__ We, const float* __restrict__ att,
                                               const float* __restrict__ bias,
                                               float* __restrict__ out, int n) {
    constexpr int HC = H * C;
    constexpr int VPL = HC / 64;   // values per lane (2 or 4)
    constexpr int RW = 64 / H;     // lanes per head
    constexpr int CH = 8;          // edges per chunk
    using GT = typename std::conditional<VPL == 2, uint32_t, uint2>::type;

    int wid = threadIdx.x >> 6;
    int lane = threadIdx.x & 63;
    int v = blockIdx.x * 4 + wid;
    if (v >= n) return;

    int base = lane * VPL;
    float xrv[VPL], wE[VPL], attv[VPL];
    if constexpr (VPL == 2) {
        uint32_t u = *(const uint32_t*)&xr[(size_t)v * HC + base];
        xrv[0] = bflo(u); xrv[1] = bfhi(u);
    } else {
        uint2 u = *(const uint2*)&xr[(size_t)v * HC + base];
        xrv[0] = bflo(u.x); xrv[1] = bfhi(u.x); xrv[2] = bflo(u.y); xrv[3] = bfhi(u.y);
    }
#pragma unroll
    for (int j = 0; j < VPL; ++j) { wE[j] = We[base + j]; attv[j] = att[base + j]; }

    const int e0 = row_start[v], e1 = row_start[v + 1];
    float m = -__builtin_inff(), den = 0.f, acc[VPL];
#pragma unroll
    for (int j = 0; j < VPL; ++j) acc[j] = 0.f;

    GT gA[CH], gB[CH];
    float wA[CH], wB[CH];

    auto issue = [&](int eb, GT (&g)[CH], float (&wb)[CH]) {
#pragma unroll
        for (int i = 0; i < CH; ++i) {
            int e = eb + i; e = e < e1 ? e : e1 - 1;   // clamp (dup tail, masked later)
            int s = csr_src[e];
            wb[i] = csr_ea[e];
            g[i] = *(const GT*)&xl[(size_t)s * HC + base];
        }
    };

    auto compute = [&](int eb, GT (&g)[CH], float (&wb)[CH]) {
        float xf[CH][VPL], p[CH];
#pragma unroll
        for (int i = 0; i < CH; ++i) {
            if constexpr (VPL == 2) {
                xf[i][0] = bflo(g[i]); xf[i][1] = bfhi(g[i]);
            } else {
                xf[i][0] = bflo(g[i].x); xf[i][1] = bfhi(g[i].x);
                xf[i][2] = bflo(g[i].y); xf[i][3] = bfhi(g[i].y);
            }
            float pp = 0.f;
#pragma unroll
            for (int j = 0; j < VPL; ++j) {
                float mm = xf[i][j] + fmaf(wb[i], wE[j], xrv[j]);
                mm = mm > 0.f ? mm : 0.2f * mm;
                pp = fmaf(mm, attv[j], pp);
            }
            p[i] = pp;
        }
#pragma unroll
        for (int i = 0; i < CH; ++i)
#pragma unroll
            for (int o = RW >> 1; o; o >>= 1) p[i] += __shfl_xor(p[i], o, 64);
#pragma unroll
        for (int i = 0; i < CH; ++i)
            if (eb + i >= e1) p[i] = -__builtin_inff();

        float pm = fmaxf(fmaxf(fmaxf(p[0], p[1]), fmaxf(p[2], p[3])),
                         fmaxf(fmaxf(p[4], p[5]), fmaxf(p[6], p[7])));
        float mn = fmaxf(m, pm);
        float sc = __expf(m - mn);
        float pe[CH];
#pragma unroll
        for (int i = 0; i < CH; ++i) pe[i] = __expf(p[i] - mn);
        float ps = (pe[0] + pe[1]) + (pe[2] + pe[3]) + ((pe[4] + pe[5]) + (pe[6] + pe[7]));
        den = fmaf(den, sc, ps);
#pragma unroll
        for (int j = 0; j < VPL; ++j) {
            float u01 = fmaf(pe[1], xf[1][j], pe[0] * xf[0][j]);
            float u23 = fmaf(pe[3], xf[3][j], pe[2] * xf[2][j]);
            float u45 = fmaf(pe[5], xf[5][j], pe[4] * xf[4][j]);
            float u67 = fmaf(pe[7], xf[7][j], pe[6] * xf[6][j]);
            float t = (u01 + u23) + (u45 + u67);
            acc[j] = fmaf(acc[j], sc, t);
        }
        m = mn;
    };

    issue(e0, gA, wA);
    int eb = e0;
    while (true) {
        if (eb + CH < e1) issue(eb + CH, gB, wB);
        compute(eb, gA, wA);
        eb += CH;
        if (eb >= e1) break;
        if (eb + CH < e1) issue(eb + CH, gA, wA);
        compute(eb, gB, wB);
        eb += CH;
        if (eb >= e1) break;
    }

    float inv = 1.f / (den + 1e-16f);
#pragma unroll
    for (int j = 0; j < VPL; ++j) acc[j] *= inv;
    // mean over heads
#pragma unroll
    for (int o = RW; o < 64; o <<= 1)
#pragma unroll
        for (int j = 0; j < VPL; ++j) acc[j] += __shfl_xor(acc[j], o, 64);

    if (lane < RW) {
#pragma unroll
        for (int j = 0; j < VPL; ++j)
            out[(size_t)v * C + base + j] = acc[j] * (1.f / (float)H) + bias[base + j];
    }
}

// ---------------------------------------------------------------- batchnorm
__global__ void bn_stats(const float* __restrict__ x, int n, int C, float* __restrict__ sums) {
    int t = threadIdx.x;
    int col = t & (C - 1);
    int rpb = 256 / C;
    int row = blockIdx.x * rpb + t / C;
    float s = 0.f, sq = 0.f;
    for (; row < n; row += gridDim.x * rpb) {
        float v = x[(size_t)row * C + col];
        s += v; sq += v * v;
    }
    atomicAdd(&sums[col], s);
    atomicAdd(&sums[C + col], sq);
}

template <bool BF16OUT>
__global__ void bn_apply_elu(const float* __restrict__ x, int n, int C,
                             const float* __restrict__ g, const float* __restrict__ be,
                             const float* __restrict__ sums,
                             float* __restrict__ outf, ushort* __restrict__ outb) {
    int total = n * C / 4;
    float invn = 1.f / (float)n;
    for (int i = blockIdx.x * blockDim.x + threadIdx.x; i < total; i += gridDim.x * blockDim.x) {
        float4 v = ((const float4*)x)[i];
        int c0 = (i * 4) & (C - 1);
        float r[4] = {v.x, v.y, v.z, v.w};
#pragma unroll
        for (int j = 0; j < 4; ++j) {
            int c = c0 + j;
            float mu = sums[c] * invn;
            float var = sums[C + c] * invn - mu * mu;
            float t = g[c] * (r[j] - mu) * rsqrtf(var + 1e-5f) + be[c];
            r[j] = t > 0.f ? t : expm1f(t);
        }
        if constexpr (BF16OUT) {
            ushort4 o;
            o.x = f2bf(r[0]); o.y = f2bf(r[1]); o.z = f2bf(r[2]); o.w = f2bf(r[3]);
            ((ushort4*)outb)[i] = o;
        } else {
            ((float4*)outf)[i] = make_float4(r[0], r[1], r[2], r[3]);
        }
    }
}

// ---------------------------------------------------------------- launch
extern "C" void kernel_launch(void* const* d_in, const int* in_sizes, int n_in,
                              void* d_out, int out_size, void* d_ws, size_t ws_size,
                              hipStream_t stream) {
    const float* emb = (const float*)d_in[0];
    const float* ew  = (const float*)d_in[1];
    const float* Wl0 = (const float*)d_in[2];
    const float* bl0 = (const float*)d_in[3];
    const float* Wr0 = (const float*)d_in[4];
    const float* br0 = (const float*)d_in[5];
    const float* We0 = (const float*)d_in[6];
    const float* att0 = (const float*)d_in[7];
    const float* b0  = (const float*)d_in[8];
    const float* g0  = (const float*)d_in[9];
    const float* be0 = (const float*)d_in[10];
    const float* Wl1 = (const float*)d_in[11];
    const float* bl1 = (const float*)d_in[12];
    const float* Wr1 = (const float*)d_in[13];
    const float* br1 = (const float*)d_in[14];
    const float* We1 = (const float*)d_in[15];
    const float* att1 = (const float*)d_in[16];
    const float* b1  = (const float*)d_in[17];
    const float* g1  = (const float*)d_in[18];
    const float* be1 = (const float*)d_in[19];
    const int* ei    = (const int*)d_in[20];

    const int N = in_sizes[0] / 128;
    const int E = in_sizes[1];
    const int Et = E + N;
    float* out = (float*)d_out;

    char* w = (char*)d_ws;
    size_t off = 0;
    auto alloc = [&](size_t bytes) {
        void* p = w + off;
        off = (off + bytes + 255) & ~(size_t)255;
        return p;
    };
    ushort* xlb    = (ushort*)alloc((size_t)N * 256 * 2);
    ushort* xrb    = (ushort*)alloc((size_t)N * 256 * 2);
    float*  h0     = (float*)alloc((size_t)N * 128 * 4);
    ushort* h0b    = (ushort*)alloc((size_t)N * 128 * 2);
    ushort* embb   = (ushort*)alloc((size_t)N * 128 * 2);
    ushort* WT0    = (ushort*)alloc((size_t)256 * 128 * 2);
    ushort* WT1    = (ushort*)alloc((size_t)512 * 128 * 2);
    int*   deg     = (int*)alloc((size_t)2 * N * 4);     // deg + cursor (one memset)
    int*   cursor  = deg + N;
    int*   row_st  = (int*)alloc((size_t)(N + 1) * 4);
    int*   csr_src = (int*)alloc((size_t)Et * 4);
    float* csr_ea  = (float*)alloc((size_t)Et * 4);
    int*   bsum    = (int*)alloc(256 * 4);
    int*   boff    = (int*)alloc(256 * 4);
    float* stats   = (float*)alloc(512 * 4);             // ew_sum + bn0 + bn1 (one memset)
    float* ew_sum  = stats;
    float* bn0     = stats + 64;
    float* bn1     = stats + 64 + 256;
    (void)ws_size; (void)n_in; (void)out_size;

    hipMemsetAsync(deg, 0, (size_t)2 * N * 4, stream);
    hipMemsetAsync(stats, 0, 512 * 4, stream);

    // CSR build + prep
    degree_kernel<<<(Et + 255) / 256, 256, 0, stream>>>(ei, ew, deg, ew_sum, E, N);
    const int NB1 = (N + 1023) / 1024;
    scan_partial<<<NB1, 256, 0, stream>>>(deg, N, bsum);
    scan_block<<<1, 256, 0, stream>>>(bsum, NB1, boff, row_st, N, Et);
    scan_final<<<NB1, 256, 0, stream>>>(deg, N, boff, row_st);
    scatter_kernel<<<(Et + 255) / 256, 256, 0, stream>>>(ei, ew, ew_sum, row_st, cursor,
                                                         csr_src, csr_ea, E, N);
    const int n4 = N * 128 / 4;
    const int prep_total = n4 + 128 * 256 + 128 * 512;
    prep_kernel<<<(prep_total + 255) / 256, 256, 0, stream>>>(emb, embb, n4,
                                                              Wl0, Wr0, WT0, Wl1, Wr1, WT1);

    const int ntiles = (N + 127) / 128;
    const int GR0 = ntiles < 128 ? ntiles : 128;
    const int GR1 = ntiles < 64 ? ntiles : 64;

    // ---- layer 0
    mfma_linear2<<<dim3(2, GR0), 512, 0, stream>>>(embb, WT0, bl0, br0, xlb, xrb, N, 128);
    gat_agg<1, 128><<<(N + 3) / 4, 256, 0, stream>>>(xlb, xrb, row_st, csr_src, csr_ea,
                                                     We0, att0, b0, h0, N);
    bn_stats<<<512, 256, 0, stream>>>(h0, N, 128, bn0);
    bn_apply_elu<true><<<2048, 256, 0, stream>>>(h0, N, 128, g0, be0, bn0, nullptr, h0b);

    // ---- layer 1
    mfma_linear2<<<dim3(4, GR1), 512, 0, stream>>>(h0b, WT1, bl1, br1, xlb, xrb, N, 256);
    gat_agg<4, 64><<<(N + 3) / 4, 256, 0, stream>>>(xlb, xrb, row_st, csr_src, csr_ea,
                                                    We1, att1, b1, out, N);
    bn_stats<<<512, 256, 0, stream>>>(out, N, 64, bn1);
    bn_apply_elu<false><<<2048, 256, 0, stream>>>(out, N, 64, g1, be1, bn1, out, nullptr);
}

// Round 4
// 383.582 us; speedup vs baseline: 1.2585x; 1.2585x over previous
//
#include <hip/hip_runtime.h>
#include <cstdint>
#include <cstddef>
#include <type_traits>

using f32x4 = __attribute__((ext_vector_type(4))) float;
using s16x8 = __attribute__((ext_vector_type(8))) short;

__device__ __forceinline__ ushort f2bf(float x) {
    uint32_t u = __builtin_bit_cast(uint32_t, x);
    u += 0x7fffu + ((u >> 16) & 1u);          // round-to-nearest-even
    return (ushort)(u >> 16);
}
__device__ __forceinline__ float bflo(uint32_t u) { return __builtin_bit_cast(float, u << 16); }
__device__ __forceinline__ float bfhi(uint32_t u) { return __builtin_bit_cast(float, u & 0xffff0000u); }

#define GLOAD_LDS16(g, l)                                                                  \
    __builtin_amdgcn_global_load_lds((const __attribute__((address_space(1))) void*)(g),  \
                                     (__attribute__((address_space(3))) void*)(l), 16, 0, 0)

// ---------------------------------------------------------------- CSR build
__global__ void degree_kernel(const int* __restrict__ ei, int* __restrict__ deg, int E, int N) {
    int e = blockIdx.x * blockDim.x + threadIdx.x;
    if (e >= E + N) return;
    int d = (e < E) ? ei[E + e] : (e - E);
    atomicAdd(&deg[d], 1);
}

// edge-weight partial sums: NO same-address atomics (plain store per block)
__global__ __launch_bounds__(256) void ew_partial_kernel(const float* __restrict__ ew, int E,
                                                          float* __restrict__ partials) {
    __shared__ float red[256];
    int t = threadIdx.x;
    float s = 0.f;
    int E4 = E >> 2;
    for (int i = blockIdx.x * 256 + t; i < E4; i += 256 * gridDim.x) {
        float4 v = ((const float4*)ew)[i];
        s += (v.x + v.y) + (v.z + v.w);
    }
    if (blockIdx.x == 0 && t < (E & 3)) s += ew[E4 * 4 + t];
    red[t] = s; __syncthreads();
    for (int o = 128; o; o >>= 1) { if (t < o) red[t] += red[t + o]; __syncthreads(); }
    if (t == 0) partials[blockIdx.x] = red[0];
}

__global__ void scan_partial(const int* __restrict__ deg, int n, int* __restrict__ bsum) {
    __shared__ int lds[256];
    int t = threadIdx.x;
    int base = blockIdx.x * 1024 + t * 4;
    int s = 0;
#pragma unroll
    for (int j = 0; j < 4; ++j) if (base + j < n) s += deg[base + j];
    lds[t] = s; __syncthreads();
    for (int o = 128; o; o >>= 1) { if (t < o) lds[t] += lds[t + o]; __syncthreads(); }
    if (t == 0) bsum[blockIdx.x] = lds[0];
}

// single block: scan of block sums + final ew mean
__global__ void scan_block(const int* __restrict__ bsum, int nb, int* __restrict__ boff,
                           int* __restrict__ row_start, int n, int total,
                           const float* __restrict__ partials, int E, float* __restrict__ ew_mean) {
    __shared__ int lds[256];
    __shared__ float fred[256];
    int t = threadIdx.x;
    int v = (t < nb) ? bsum[t] : 0;
    lds[t] = v; __syncthreads();
    for (int o = 1; o < 256; o <<= 1) {
        int y = (t >= o) ? lds[t - o] : 0;
        __syncthreads();
        lds[t] += y;
        __syncthreads();
    }
    if (t < nb) boff[t] = lds[t] - v;   // exclusive
    if (t == 0) row_start[n] = total;
    // reduce ew partials
    fred[t] = partials[t]; __syncthreads();
    for (int o = 128; o; o >>= 1) { if (t < o) fred[t] += fred[t + o]; __syncthreads(); }
    if (t == 0) ew_mean[0] = fred[0] / (float)E;
}

__global__ void scan_final(const int* __restrict__ deg, int n, const int* __restrict__ boff,
                           int* __restrict__ row_start) {
    __shared__ int lds[256];
    int t = threadIdx.x;
    int base = blockIdx.x * 1024 + t * 4;
    int d[4], loc[4], s = 0;
#pragma unroll
    for (int j = 0; j < 4; ++j) d[j] = (base + j < n) ? deg[base + j] : 0;
#pragma unroll
    for (int j = 0; j < 4; ++j) { loc[j] = s; s += d[j]; }
    lds[t] = s; __syncthreads();
    for (int o = 1; o < 256; o <<= 1) {
        int y = (t >= o) ? lds[t - o] : 0;
        __syncthreads();
        lds[t] += y;
        __syncthreads();
    }
    int texcl = lds[t] - s + boff[blockIdx.x];
#pragma unroll
    for (int j = 0; j < 4; ++j) if (base + j < n) row_start[base + j] = texcl + loc[j];
}

__global__ void scatter_kernel(const int* __restrict__ ei, const float* __restrict__ ew,
                               const float* __restrict__ ew_mean, const int* __restrict__ row_start,
                               int* __restrict__ cursor, int* __restrict__ csr_src,
                               float* __restrict__ csr_ea, int E, int N) {
    int e = blockIdx.x * blockDim.x + threadIdx.x;
    if (e >= E + N) return;
    int s, d; float w;
    if (e < E) { s = ei[e]; d = ei[E + e]; w = ew[e]; }
    else       { s = d = e - E;            w = ew_mean[0]; }
    int pos = row_start[d] + atomicAdd(&cursor[d], 1);
    csr_src[pos] = s;
    csr_ea[pos] = w;
}

// ---------------------------------------------------------------- prep: emb->bf16 + WT builds
__global__ void prep_kernel(const float* __restrict__ emb, ushort* __restrict__ embb, int n4,
                            const float* __restrict__ Wl0, const float* __restrict__ Wr0,
                            ushort* __restrict__ WT0,
                            const float* __restrict__ Wl1, const float* __restrict__ Wr1,
                            ushort* __restrict__ WT1) {
    int i = blockIdx.x * 256 + threadIdx.x;
    if (i < n4) {
        float4 v = ((const float4*)emb)[i];
        ushort4 o;
        o.x = f2bf(v.x); o.y = f2bf(v.y); o.z = f2bf(v.z); o.w = f2bf(v.w);
        ((ushort4*)embb)[i] = o;
        return;
    }
    int j = i - n4;
    if (j < 128 * 256) {
        int k = j >> 8, c = j & 255;
        float v = (c < 128) ? Wl0[k * 128 + c] : Wr0[k * 128 + (c - 128)];
        WT0[(size_t)c * 128 + k] = f2bf(v);
        return;
    }
    j -= 128 * 256;
    if (j < 128 * 512) {
        int k = j >> 9, c = j & 511;
        float v = (c < 256) ? Wl1[k * 256 + c] : Wr1[k * 256 + (c - 256)];
        WT1[(size_t)c * 128 + k] = f2bf(v);
    }
}

// ---------------------------------------------------------------- persistent col-panel MFMA GEMM
__global__ __launch_bounds__(512) void mfma_linear2(const ushort* __restrict__ Xb,
                                                    const ushort* __restrict__ WT,
                                                    const float* __restrict__ bl,
                                                    const float* __restrict__ br,
                                                    ushort* __restrict__ xl,
                                                    ushort* __restrict__ xr,
                                                    int n, int HALF) {
    __shared__ ushort sB[128 * 128];
    __shared__ ushort sA[2][128 * 128];
    const int tid = threadIdx.x;
    const int c0 = blockIdx.x * 128;
    const int ntiles = (n + 127) >> 7;

    {
        const ushort* src = WT + (size_t)c0 * 128;
#pragma unroll
        for (int it = 0; it < 4; ++it) {
            int f = tid + it * 512;
            int row = f >> 4, ch = f & 15;
            const ushort* g = src + (size_t)row * 128 + ((ch ^ (row & 7)) << 3);
            ushort* lp = sB + (((size_t)it * 512 + (tid & ~63)) << 3);
            GLOAD_LDS16(g, lp);
        }
    }

    auto stageA = [&](ushort* dstLds, int rt) {
        int r0 = rt << 7;
#pragma unroll
        for (int it = 0; it < 4; ++it) {
            int f = tid + it * 512;
            int row = f >> 4, ch = f & 15;
            int gr = r0 + row; gr = gr < n ? gr : n - 1;
            const ushort* g = Xb + (size_t)gr * 128 + ((ch ^ (row & 7)) << 3);
            ushort* lp = dstLds + (((size_t)it * 512 + (tid & ~63)) << 3);
            GLOAD_LDS16(g, lp);
        }
    };

    const int w = tid >> 6, l = tid & 63, lr = l & 15, lg = l >> 4;
    const bool left = c0 < HALF;
    const float* bias = left ? bl : br;
    ushort* dst = left ? xl : xr;
    const int cb = left ? c0 : c0 - HALF;
    float bv[8];
#pragma unroll
    for (int tn = 0; tn < 8; ++tn) bv[tn] = bias[cb + tn * 16 + lr];

    int rt = blockIdx.y;
    stageA(sA[0], rt);
    __syncthreads();

    int cur = 0;
    const int arow = w * 16 + lr;
    while (true) {
        int nx = rt + gridDim.y;
        if (nx < ntiles) stageA(sA[cur ^ 1], nx);

        f32x4 acc[8] = {};
        const ushort* sAc = sA[cur];
#pragma unroll
        for (int kk = 0; kk < 4; ++kk) {
            int ach = (kk * 4 + lg) ^ (arow & 7);
            s16x8 a = *(const s16x8*)&sAc[arow * 128 + (ach << 3)];
#pragma unroll
            for (int tn = 0; tn < 8; ++tn) {
                int brow = tn * 16 + lr;
                int bch = (kk * 4 + lg) ^ (brow & 7);
                s16x8 b = *(const s16x8*)&sB[brow * 128 + (bch << 3)];
                acc[tn] = __builtin_amdgcn_mfma_f32_16x16x32_bf16(a, b, acc[tn], 0, 0, 0);
            }
        }
        int rbase = (rt << 7) + w * 16 + lg * 4;
#pragma unroll
        for (int tn = 0; tn < 8; ++tn) {
            int colh = cb + tn * 16 + lr;
#pragma unroll
            for (int r = 0; r < 4; ++r) {
                int row = rbase + r;
                if (row < n) dst[(size_t)row * HALF + colh] = f2bf(acc[tn][r] + bv[tn]);
            }
        }
        if (nx >= ntiles) break;
        __syncthreads();
        cur ^= 1; rt = nx;
    }
}

// ---------------------------------------------------------------- GATv2 aggregation (bf16 out)
template <int H, int C>
__global__ __launch_bounds__(256) void gat_agg(const ushort* __restrict__ xl, const ushort* __restrict__ xr,
                                               const int* __restrict__ row_start,
                                               const int* __restrict__ csr_src,
                                               const float* __restrict__ csr_ea,
                                               const float* __restrict__ We, const float* __restrict__ att,
                                               const float* __restrict__ bias,
                                               ushort* __restrict__ out, int n) {
    constexpr int HC = H * C;
    constexpr int VPL = HC / 64;   // values per lane (2 or 4)
    constexpr int RW = 64 / H;     // lanes per head
    constexpr int CH = 8;          // edges per chunk
    using GT = typename std::conditional<VPL == 2, uint32_t, uint2>::type;

    int wid = threadIdx.x >> 6;
    int lane = threadIdx.x & 63;
    int v = blockIdx.x * 4 + wid;
    if (v >= n) return;

    int base = lane * VPL;
    float xrv[VPL], wE[VPL], attv[VPL];
    if constexpr (VPL == 2) {
        uint32_t u = *(const uint32_t*)&xr[(size_t)v * HC + base];
        xrv[0] = bflo(u); xrv[1] = bfhi(u);
    } else {
        uint2 u = *(const uint2*)&xr[(size_t)v * HC + base];
        xrv[0] = bflo(u.x); xrv[1] = bfhi(u.x); xrv[2] = bflo(u.y); xrv[3] = bfhi(u.y);
    }
#pragma unroll
    for (int j = 0; j < VPL; ++j) { wE[j] = We[base + j]; attv[j] = att[base + j]; }

    const int e0 = row_start[v], e1 = row_start[v + 1];
    float m = -__builtin_inff(), den = 0.f, acc[VPL];
#pragma unroll
    for (int j = 0; j < VPL; ++j) acc[j] = 0.f;

    GT gA[CH], gB[CH];
    float wA[CH], wB[CH];

    auto issue = [&](int eb, GT (&g)[CH], float (&wb)[CH]) {
#pragma unroll
        for (int i = 0; i < CH; ++i) {
            int e = eb + i; e = e < e1 ? e : e1 - 1;   // clamp (dup tail, masked later)
            int s = csr_src[e];
            wb[i] = csr_ea[e];
            g[i] = *(const GT*)&xl[(size_t)s * HC + base];
        }
    };

    auto compute = [&](int eb, GT (&g)[CH], float (&wb)[CH]) {
        float xf[CH][VPL], p[CH];
#pragma unroll
        for (int i = 0; i < CH; ++i) {
            if constexpr (VPL == 2) {
                xf[i][0] = bflo(g[i]); xf[i][1] = bfhi(g[i]);
            } else {
                xf[i][0] = bflo(g[i].x); xf[i][1] = bfhi(g[i].x);
                xf[i][2] = bflo(g[i].y); xf[i][3] = bfhi(g[i].y);
            }
            float pp = 0.f;
#pragma unroll
            for (int j = 0; j < VPL; ++j) {
                float mm = xf[i][j] + fmaf(wb[i], wE[j], xrv[j]);
                mm = mm > 0.f ? mm : 0.2f * mm;
                pp = fmaf(mm, attv[j], pp);
            }
            p[i] = pp;
        }
#pragma unroll
        for (int i = 0; i < CH; ++i)
#pragma unroll
            for (int o = RW >> 1; o; o >>= 1) p[i] += __shfl_xor(p[i], o, 64);
#pragma unroll
        for (int i = 0; i < CH; ++i)
            if (eb + i >= e1) p[i] = -__builtin_inff();

        float pm = fmaxf(fmaxf(fmaxf(p[0], p[1]), fmaxf(p[2], p[3])),
                         fmaxf(fmaxf(p[4], p[5]), fmaxf(p[6], p[7])));
        float mn = fmaxf(m, pm);
        float sc = __expf(m - mn);
        float pe[CH];
#pragma unroll
        for (int i = 0; i < CH; ++i) pe[i] = __expf(p[i] - mn);
        float ps = (pe[0] + pe[1]) + (pe[2] + pe[3]) + ((pe[4] + pe[5]) + (pe[6] + pe[7]));
        den = fmaf(den, sc, ps);
#pragma unroll
        for (int j = 0; j < VPL; ++j) {
            float u01 = fmaf(pe[1], xf[1][j], pe[0] * xf[0][j]);
            float u23 = fmaf(pe[3], xf[3][j], pe[2] * xf[2][j]);
            float u45 = fmaf(pe[5], xf[5][j], pe[4] * xf[4][j]);
            float u67 = fmaf(pe[7], xf[7][j], pe[6] * xf[6][j]);
            float t = (u01 + u23) + (u45 + u67);
            acc[j] = fmaf(acc[j], sc, t);
        }
        m = mn;
    };

    issue(e0, gA, wA);
    int eb = e0;
    while (true) {
        if (eb + CH < e1) issue(eb + CH, gB, wB);
        compute(eb, gA, wA);
        eb += CH;
        if (eb >= e1) break;
        if (eb + CH < e1) issue(eb + CH, gA, wA);
        compute(eb, gB, wB);
        eb += CH;
        if (eb >= e1) break;
    }

    float inv = 1.f / (den + 1e-16f);
#pragma unroll
    for (int j = 0; j < VPL; ++j) acc[j] *= inv;
    // mean over heads
#pragma unroll
    for (int o = RW; o < 64; o <<= 1)
#pragma unroll
        for (int j = 0; j < VPL; ++j) acc[j] += __shfl_xor(acc[j], o, 64);

    if (lane < RW) {
#pragma unroll
        for (int j = 0; j < VPL; ++j)
            out[(size_t)v * C + base + j] = f2bf(acc[j] * (1.f / (float)H) + bias[base + j]);
    }
}

// ---------------------------------------------------------------- batchnorm (bf16 in)
// per-block LDS reduce -> 1 atomic per column per block (gridDim per address)
template <int C>
__global__ __launch_bounds__(256) void bn_stats_bf16(const ushort* __restrict__ x, int n,
                                                     float* __restrict__ sums) {
    constexpr int C2 = C / 2;
    constexpr int RPB = 256 / C2;
    __shared__ float red[256];
    int t = threadIdx.x;
    int c2 = t % C2, rs = t / C2;
    float s0 = 0.f, s1 = 0.f, q0 = 0.f, q1 = 0.f;
    for (int row = blockIdx.x * RPB + rs; row < n; row += gridDim.x * RPB) {
        uint32_t u = *(const uint32_t*)&x[(size_t)row * C + c2 * 2];
        float a = bflo(u), b = bfhi(u);
        s0 += a; q0 += a * a; s1 += b; q1 += b * b;
    }
    float vals[4] = {s0, s1, q0, q1};
    float outv[4];
#pragma unroll
    for (int k = 0; k < 4; ++k) {
        red[t] = vals[k]; __syncthreads();
        if (rs == 0) {
            float s = red[c2];
#pragma unroll
            for (int r = 1; r < RPB; ++r) s += red[c2 + r * C2];
            outv[k] = s;
        }
        __syncthreads();
    }
    if (rs == 0) {
        atomicAdd(&sums[c2 * 2],     outv[0]);
        atomicAdd(&sums[c2 * 2 + 1], outv[1]);
        atomicAdd(&sums[C + c2 * 2],     outv[2]);
        atomicAdd(&sums[C + c2 * 2 + 1], outv[3]);
    }
}

template <int C, bool F32OUT>
__global__ __launch_bounds__(256) void bn_apply_elu2(const ushort* __restrict__ x, int n,
                                                     const float* __restrict__ g,
                                                     const float* __restrict__ be,
                                                     const float* __restrict__ sums,
                                                     ushort* __restrict__ outb,
                                                     float* __restrict__ outf) {
    int total = n * C / 8;
    float invn = 1.f / (float)n;
    for (int i = blockIdx.x * blockDim.x + threadIdx.x; i < total; i += gridDim.x * blockDim.x) {
        uint4 u = ((const uint4*)x)[i];
        int c0 = (i * 8) & (C - 1);
        float r[8] = {bflo(u.x), bfhi(u.x), bflo(u.y), bfhi(u.y),
                      bflo(u.z), bfhi(u.z), bflo(u.w), bfhi(u.w)};
#pragma unroll
        for (int j = 0; j < 8; ++j) {
            int c = c0 + j;
            float mu = sums[c] * invn;
            float var = sums[C + c] * invn - mu * mu;
            float t = g[c] * (r[j] - mu) * rsqrtf(var + 1e-5f) + be[c];
            r[j] = t > 0.f ? t : expm1f(t);
        }
        if constexpr (F32OUT) {
            ((float4*)outf)[i * 2]     = make_float4(r[0], r[1], r[2], r[3]);
            ((float4*)outf)[i * 2 + 1] = make_float4(r[4], r[5], r[6], r[7]);
        } else {
            uint4 o;
            o.x = (uint32_t)f2bf(r[0]) | ((uint32_t)f2bf(r[1]) << 16);
            o.y = (uint32_t)f2bf(r[2]) | ((uint32_t)f2bf(r[3]) << 16);
            o.z = (uint32_t)f2bf(r[4]) | ((uint32_t)f2bf(r[5]) << 16);
            o.w = (uint32_t)f2bf(r[6]) | ((uint32_t)f2bf(r[7]) << 16);
            ((uint4*)outb)[i] = o;
        }
    }
}

// ---------------------------------------------------------------- launch
extern "C" void kernel_launch(void* const* d_in, const int* in_sizes, int n_in,
                              void* d_out, int out_size, void* d_ws, size_t ws_size,
                              hipStream_t stream) {
    const float* emb = (const float*)d_in[0];
    const float* ew  = (const float*)d_in[1];
    const float* Wl0 = (const float*)d_in[2];
    const float* bl0 = (const float*)d_in[3];
    const float* Wr0 = (const float*)d_in[4];
    const float* br0 = (const float*)d_in[5];
    const float* We0 = (const float*)d_in[6];
    const float* att0 = (const float*)d_in[7];
    const float* b0  = (const float*)d_in[8];
    const float* g0  = (const float*)d_in[9];
    const float* be0 = (const float*)d_in[10];
    const float* Wl1 = (const float*)d_in[11];
    const float* bl1 = (const float*)d_in[12];
    const float* Wr1 = (const float*)d_in[13];
    const float* br1 = (const float*)d_in[14];
    const float* We1 = (const float*)d_in[15];
    const float* att1 = (const float*)d_in[16];
    const float* b1  = (const float*)d_in[17];
    const float* g1  = (const float*)d_in[18];
    const float* be1 = (const float*)d_in[19];
    const int* ei    = (const int*)d_in[20];

    const int N = in_sizes[0] / 128;
    const int E = in_sizes[1];
    const int Et = E + N;
    float* out = (float*)d_out;

    char* w = (char*)d_ws;
    size_t off = 0;
    auto alloc = [&](size_t bytes) {
        void* p = w + off;
        off = (off + bytes + 255) & ~(size_t)255;
        return p;
    };
    ushort* xlb    = (ushort*)alloc((size_t)N * 256 * 2);
    ushort* xrb    = (ushort*)alloc((size_t)N * 256 * 2);
    ushort* h0b16  = (ushort*)alloc((size_t)N * 128 * 2);   // gat0 out (pre-BN), then in-place post-BN
    ushort* out16  = (ushort*)alloc((size_t)N * 64 * 2);    // gat1 out (pre-BN)
    ushort* embb   = (ushort*)alloc((size_t)N * 128 * 2);
    ushort* WT0    = (ushort*)alloc((size_t)256 * 128 * 2);
    ushort* WT1    = (ushort*)alloc((size_t)512 * 128 * 2);
    int*   deg     = (int*)alloc((size_t)2 * N * 4);        // deg + cursor (one memset)
    int*   cursor  = deg + N;
    int*   row_st  = (int*)alloc((size_t)(N + 1) * 4);
    int*   csr_src = (int*)alloc((size_t)Et * 4);
    float* csr_ea  = (float*)alloc((size_t)Et * 4);
    int*   bsum    = (int*)alloc(256 * 4);
    int*   boff    = (int*)alloc(256 * 4);
    float* partials= (float*)alloc(256 * 4);
    float* stats   = (float*)alloc(512 * 4);                // ew_mean + bn0 + bn1 (one memset)
    float* ew_mean = stats;
    float* bn0     = stats + 64;
    float* bn1     = stats + 64 + 256;
    (void)ws_size; (void)n_in; (void)out_size;

    hipMemsetAsync(deg, 0, (size_t)2 * N * 4, stream);
    hipMemsetAsync(stats, 0, 512 * 4, stream);

    // CSR build + prep
    degree_kernel<<<(Et + 255) / 256, 256, 0, stream>>>(ei, deg, E, N);
    ew_partial_kernel<<<256, 256, 0, stream>>>(ew, E, partials);
    const int NB1 = (N + 1023) / 1024;
    scan_partial<<<NB1, 256, 0, stream>>>(deg, N, bsum);
    scan_block<<<1, 256, 0, stream>>>(bsum, NB1, boff, row_st, N, Et, partials, E, ew_mean);
    scan_final<<<NB1, 256, 0, stream>>>(deg, N, boff, row_st);
    scatter_kernel<<<(Et + 255) / 256, 256, 0, stream>>>(ei, ew, ew_mean, row_st, cursor,
                                                         csr_src, csr_ea, E, N);
    const int n4 = N * 128 / 4;
    const int prep_total = n4 + 128 * 256 + 128 * 512;
    prep_kernel<<<(prep_total + 255) / 256, 256, 0, stream>>>(emb, embb, n4,
                                                              Wl0, Wr0, WT0, Wl1, Wr1, WT1);

    const int ntiles = (N + 127) / 128;
    const int GR0 = ntiles < 128 ? ntiles : 128;
    const int GR1 = ntiles < 64 ? ntiles : 64;

    // ---- layer 0
    mfma_linear2<<<dim3(2, GR0), 512, 0, stream>>>(embb, WT0, bl0, br0, xlb, xrb, N, 128);
    gat_agg<1, 128><<<(N + 3) / 4, 256, 0, stream>>>(xlb, xrb, row_st, csr_src, csr_ea,
                                                     We0, att0, b0, h0b16, N);
    bn_stats_bf16<128><<<128, 256, 0, stream>>>(h0b16, N, bn0);
    bn_apply_elu2<128, false><<<1024, 256, 0, stream>>>(h0b16, N, g0, be0, bn0, h0b16, nullptr);

    // ---- layer 1
    mfma_linear2<<<dim3(4, GR1), 512, 0, stream>>>(h0b16, WT1, bl1, br1, xlb, xrb, N, 256);
    gat_agg<4, 64><<<(N + 3) / 4, 256, 0, stream>>>(xlb, xrb, row_st, csr_src, csr_ea,
                                                    We1, att1, b1, out16, N);
    bn_stats_bf16<64><<<128, 256, 0, stream>>>(out16, N, bn1);
    bn_apply_elu2<64, true><<<1024, 256, 0, stream>>>(out16, N, g1, be1, bn1, nullptr, out);
}

// Round 5
// 374.922 us; speedup vs baseline: 1.2875x; 1.0231x over previous
//
#include <hip/hip_runtime.h>
#include <cstdint>
#include <cstddef>
#include <type_traits>

using f32x4 = __attribute__((ext_vector_type(4))) float;
using s16x8 = __attribute__((ext_vector_type(8))) short;

__device__ __forceinline__ ushort f2bf(float x) {
    uint32_t u = __builtin_bit_cast(uint32_t, x);
    u += 0x7fffu + ((u >> 16) & 1u);          // round-to-nearest-even
    return (ushort)(u >> 16);
}
__device__ __forceinline__ float bflo(uint32_t u) { return __builtin_bit_cast(float, u << 16); }
__device__ __forceinline__ float bfhi(uint32_t u) { return __builtin_bit_cast(float, u & 0xffff0000u); }

#define GLOAD_LDS16(g, l)                                                                  \
    __builtin_amdgcn_global_load_lds((const __attribute__((address_space(1))) void*)(g),  \
                                     (__attribute__((address_space(3))) void*)(l), 16, 0, 0)

// ---------------------------------------------------------------- CSR build
__global__ void degree_kernel(const int* __restrict__ ei, int* __restrict__ deg, int E, int N) {
    int e = blockIdx.x * blockDim.x + threadIdx.x;
    if (e >= E + N) return;
    int d = (e < E) ? ei[E + e] : (e - E);
    atomicAdd(&deg[d], 1);
}

// edge-weight partial sums: NO same-address atomics (plain store per block)
__global__ __launch_bounds__(256) void ew_partial_kernel(const float* __restrict__ ew, int E,
                                                          float* __restrict__ partials) {
    __shared__ float red[256];
    int t = threadIdx.x;
    float s = 0.f;
    int E4 = E >> 2;
    for (int i = blockIdx.x * 256 + t; i < E4; i += 256 * gridDim.x) {
        float4 v = ((const float4*)ew)[i];
        s += (v.x + v.y) + (v.z + v.w);
    }
    if (blockIdx.x == 0 && t < (E & 3)) s += ew[E4 * 4 + t];
    red[t] = s; __syncthreads();
    for (int o = 128; o; o >>= 1) { if (t < o) red[t] += red[t + o]; __syncthreads(); }
    if (t == 0) partials[blockIdx.x] = red[0];
}

__global__ void scan_partial(const int* __restrict__ deg, int n, int* __restrict__ bsum) {
    __shared__ int lds[256];
    int t = threadIdx.x;
    int base = blockIdx.x * 1024 + t * 4;
    int s = 0;
#pragma unroll
    for (int j = 0; j < 4; ++j) if (base + j < n) s += deg[base + j];
    lds[t] = s; __syncthreads();
    for (int o = 128; o; o >>= 1) { if (t < o) lds[t] += lds[t + o]; __syncthreads(); }
    if (t == 0) bsum[blockIdx.x] = lds[0];
}

// single block: scan of block sums + final ew mean
__global__ void scan_block(const int* __restrict__ bsum, int nb, int* __restrict__ boff,
                           int* __restrict__ row_start, int n, int total,
                           const float* __restrict__ partials, int E, float* __restrict__ ew_mean) {
    __shared__ int lds[256];
    __shared__ float fred[256];
    int t = threadIdx.x;
    int v = (t < nb) ? bsum[t] : 0;
    lds[t] = v; __syncthreads();
    for (int o = 1; o < 256; o <<= 1) {
        int y = (t >= o) ? lds[t - o] : 0;
        __syncthreads();
        lds[t] += y;
        __syncthreads();
    }
    if (t < nb) boff[t] = lds[t] - v;   // exclusive
    if (t == 0) row_start[n] = total;
    // reduce ew partials
    fred[t] = partials[t]; __syncthreads();
    for (int o = 128; o; o >>= 1) { if (t < o) fred[t] += fred[t + o]; __syncthreads(); }
    if (t == 0) ew_mean[0] = fred[0] / (float)E;
}

__global__ void scan_final(const int* __restrict__ deg, int n, const int* __restrict__ boff,
                           int* __restrict__ row_start) {
    __shared__ int lds[256];
    int t = threadIdx.x;
    int base = blockIdx.x * 1024 + t * 4;
    int d[4], loc[4], s = 0;
#pragma unroll
    for (int j = 0; j < 4; ++j) d[j] = (base + j < n) ? deg[base + j] : 0;
#pragma unroll
    for (int j = 0; j < 4; ++j) { loc[j] = s; s += d[j]; }
    lds[t] = s; __syncthreads();
    for (int o = 1; o < 256; o <<= 1) {
        int y = (t >= o) ? lds[t - o] : 0;
        __syncthreads();
        lds[t] += y;
        __syncthreads();
    }
    int texcl = lds[t] - s + boff[blockIdx.x];
#pragma unroll
    for (int j = 0; j < 4; ++j) if (base + j < n) row_start[base + j] = texcl + loc[j];
}

__global__ void scatter_kernel(const int* __restrict__ ei, const float* __restrict__ ew,
                               const float* __restrict__ ew_mean, const int* __restrict__ row_start,
                               int* __restrict__ cursor, int* __restrict__ csr_src,
                               float* __restrict__ csr_ea, int E, int N) {
    int e = blockIdx.x * blockDim.x + threadIdx.x;
    if (e >= E + N) return;
    int s, d; float w;
    if (e < E) { s = ei[e]; d = ei[E + e]; w = ew[e]; }
    else       { s = d = e - E;            w = ew_mean[0]; }
    int pos = row_start[d] + atomicAdd(&cursor[d], 1);
    csr_src[pos] = s;
    csr_ea[pos] = w;
}

// ---------------------------------------------------------------- prep: emb->bf16 + WT builds
__global__ void prep_kernel(const float* __restrict__ emb, ushort* __restrict__ embb, int n4,
                            const float* __restrict__ Wl0, const float* __restrict__ Wr0,
                            ushort* __restrict__ WT0,
                            const float* __restrict__ Wl1, const float* __restrict__ Wr1,
                            ushort* __restrict__ WT1) {
    int i = blockIdx.x * 256 + threadIdx.x;
    if (i < n4) {
        float4 v = ((const float4*)emb)[i];
        ushort4 o;
        o.x = f2bf(v.x); o.y = f2bf(v.y); o.z = f2bf(v.z); o.w = f2bf(v.w);
        ((ushort4*)embb)[i] = o;
        return;
    }
    int j = i - n4;
    if (j < 128 * 256) {
        int k = j >> 8, c = j & 255;
        float v = (c < 128) ? Wl0[k * 128 + c] : Wr0[k * 128 + (c - 128)];
        WT0[(size_t)c * 128 + k] = f2bf(v);
        return;
    }
    j -= 128 * 256;
    if (j < 128 * 512) {
        int k = j >> 9, c = j & 511;
        float v = (c < 256) ? Wl1[k * 256 + c] : Wr1[k * 256 + (c - 256)];
        WT1[(size_t)c * 128 + k] = f2bf(v);
    }
}

// ---------------------------------------------------------------- persistent col-panel MFMA GEMM
__global__ __launch_bounds__(512) void mfma_linear2(const ushort* __restrict__ Xb,
                                                    const ushort* __restrict__ WT,
                                                    const float* __restrict__ bl,
                                                    const float* __restrict__ br,
                                                    ushort* __restrict__ xl,
                                                    ushort* __restrict__ xr,
                                                    int n, int HALF) {
    __shared__ ushort sB[128 * 128];
    __shared__ ushort sA[2][128 * 128];
    const int tid = threadIdx.x;
    const int c0 = blockIdx.x * 128;
    const int ntiles = (n + 127) >> 7;

    {
        const ushort* src = WT + (size_t)c0 * 128;
#pragma unroll
        for (int it = 0; it < 4; ++it) {
            int f = tid + it * 512;
            int row = f >> 4, ch = f & 15;
            const ushort* g = src + (size_t)row * 128 + ((ch ^ (row & 7)) << 3);
            ushort* lp = sB + (((size_t)it * 512 + (tid & ~63)) << 3);
            GLOAD_LDS16(g, lp);
        }
    }

    auto stageA = [&](ushort* dstLds, int rt) {
        int r0 = rt << 7;
#pragma unroll
        for (int it = 0; it < 4; ++it) {
            int f = tid + it * 512;
            int row = f >> 4, ch = f & 15;
            int gr = r0 + row; gr = gr < n ? gr : n - 1;
            const ushort* g = Xb + (size_t)gr * 128 + ((ch ^ (row & 7)) << 3);
            ushort* lp = dstLds + (((size_t)it * 512 + (tid & ~63)) << 3);
            GLOAD_LDS16(g, lp);
        }
    };

    const int w = tid >> 6, l = tid & 63, lr = l & 15, lg = l >> 4;
    const bool left = c0 < HALF;
    const float* bias = left ? bl : br;
    ushort* dst = left ? xl : xr;
    const int cb = left ? c0 : c0 - HALF;
    float bv[8];
#pragma unroll
    for (int tn = 0; tn < 8; ++tn) bv[tn] = bias[cb + tn * 16 + lr];

    int rt = blockIdx.y;
    stageA(sA[0], rt);
    __syncthreads();

    int cur = 0;
    const int arow = w * 16 + lr;
    while (true) {
        int nx = rt + gridDim.y;
        if (nx < ntiles) stageA(sA[cur ^ 1], nx);

        f32x4 acc[8] = {};
        const ushort* sAc = sA[cur];
#pragma unroll
        for (int kk = 0; kk < 4; ++kk) {
            int ach = (kk * 4 + lg) ^ (arow & 7);
            s16x8 a = *(const s16x8*)&sAc[arow * 128 + (ach << 3)];
#pragma unroll
            for (int tn = 0; tn < 8; ++tn) {
                int brow = tn * 16 + lr;
                int bch = (kk * 4 + lg) ^ (brow & 7);
                s16x8 b = *(const s16x8*)&sB[brow * 128 + (bch << 3)];
                acc[tn] = __builtin_amdgcn_mfma_f32_16x16x32_bf16(a, b, acc[tn], 0, 0, 0);
            }
        }
        int rbase = (rt << 7) + w * 16 + lg * 4;
#pragma unroll
        for (int tn = 0; tn < 8; ++tn) {
            int colh = cb + tn * 16 + lr;
#pragma unroll
            for (int r = 0; r < 4; ++r) {
                int row = rbase + r;
                if (row < n) dst[(size_t)row * HALF + colh] = f2bf(acc[tn][r] + bv[tn]);
            }
        }
        if (nx >= ntiles) break;
        __syncthreads();
        cur ^= 1; rt = nx;
    }
}

// ---------------------------------------------------------------- GATv2 aggregation (bf16 out)
// one wave per dst node; MINIMUM-VGPR single online-softmax chain with 1-deep
// row prefetch. Gather rate scales with resident waves (occ ~ 1/VGPR law from
// r1/r2/r4 counters), so concurrency > per-wave ILP here (avg degree ~9).
template <int H, int C>
__global__ __launch_bounds__(256, 8) void gat_agg(const ushort* __restrict__ xl,
                                                  const ushort* __restrict__ xr,
                                                  const int* __restrict__ row_start,
                                                  const int* __restrict__ csr_src,
                                                  const float* __restrict__ csr_ea,
                                                  const float* __restrict__ We,
                                                  const float* __restrict__ att,
                                                  const float* __restrict__ bias,
                                                  ushort* __restrict__ out, int n) {
    constexpr int HC = H * C;
    constexpr int VPL = HC / 64;   // values per lane (2 or 4)
    constexpr int RW = 64 / H;     // lanes per head
    using GT = typename std::conditional<VPL == 2, uint32_t, uint2>::type;

    int wid = threadIdx.x >> 6;
    int lane = threadIdx.x & 63;
    int v = blockIdx.x * 4 + wid;
    if (v >= n) return;

    const int e0 = row_start[v], e1 = row_start[v + 1];

    int base = lane * VPL;
    // 1-deep prefetch of first edge (issue before loading per-node params)
    GT gN{}; float wN = 0.f;
    if (e0 < e1) {
        int s = csr_src[e0];
        wN = csr_ea[e0];
        gN = *(const GT*)&xl[(size_t)s * HC + base];
    }

    float xrv[VPL], wE[VPL], attv[VPL];
    if constexpr (VPL == 2) {
        uint32_t u = *(const uint32_t*)&xr[(size_t)v * HC + base];
        xrv[0] = bflo(u); xrv[1] = bfhi(u);
    } else {
        uint2 u = *(const uint2*)&xr[(size_t)v * HC + base];
        xrv[0] = bflo(u.x); xrv[1] = bfhi(u.x); xrv[2] = bflo(u.y); xrv[3] = bfhi(u.y);
    }
#pragma unroll
    for (int j = 0; j < VPL; ++j) { wE[j] = We[base + j]; attv[j] = att[base + j]; }

    float m = -__builtin_inff(), den = 0.f, acc[VPL];
#pragma unroll
    for (int j = 0; j < VPL; ++j) acc[j] = 0.f;

    for (int e = e0; e < e1; ++e) {
        GT g = gN; float w = wN;
        if (e + 1 < e1) {                      // prefetch next row before compute
            int s = csr_src[e + 1];
            wN = csr_ea[e + 1];
            gN = *(const GT*)&xl[(size_t)s * HC + base];
        }
        float xf[VPL];
        if constexpr (VPL == 2) {
            xf[0] = bflo(g); xf[1] = bfhi(g);
        } else {
            xf[0] = bflo(g.x); xf[1] = bfhi(g.x); xf[2] = bflo(g.y); xf[3] = bfhi(g.y);
        }
        float p = 0.f;
#pragma unroll
        for (int j = 0; j < VPL; ++j) {
            float mm = xf[j] + fmaf(w, wE[j], xrv[j]);
            mm = mm > 0.f ? mm : 0.2f * mm;
            p = fmaf(mm, attv[j], p);
        }
#pragma unroll
        for (int o = RW >> 1; o; o >>= 1) p += __shfl_xor(p, o, 64);
        // single-exp online update; first edge: d=+inf -> sc=0, pe=1
        float d = p - m;
        bool up = d > 0.f;
        float t = __expf(up ? -d : d);
        float sc = up ? t : 1.f;
        float pe = up ? 1.f : t;
        m = up ? p : m;
        den = fmaf(den, sc, pe);
#pragma unroll
        for (int j = 0; j < VPL; ++j) acc[j] = fmaf(acc[j], sc, pe * xf[j]);
    }

    float inv = 1.f / (den + 1e-16f);
#pragma unroll
    for (int j = 0; j < VPL; ++j) acc[j] *= inv;
    // mean over heads
#pragma unroll
    for (int o = RW; o < 64; o <<= 1)
#pragma unroll
        for (int j = 0; j < VPL; ++j) acc[j] += __shfl_xor(acc[j], o, 64);

    if (lane < RW) {
#pragma unroll
        for (int j = 0; j < VPL; ++j)
            out[(size_t)v * C + base + j] = f2bf(acc[j] * (1.f / (float)H) + bias[base + j]);
    }
}

// ---------------------------------------------------------------- batchnorm (bf16 in)
template <int C>
__global__ __launch_bounds__(256) void bn_stats_bf16(const ushort* __restrict__ x, int n,
                                                     float* __restrict__ sums) {
    constexpr int C2 = C / 2;
    constexpr int RPB = 256 / C2;
    __shared__ float red[256];
    int t = threadIdx.x;
    int c2 = t % C2, rs = t / C2;
    float s0 = 0.f, s1 = 0.f, q0 = 0.f, q1 = 0.f;
    for (int row = blockIdx.x * RPB + rs; row < n; row += gridDim.x * RPB) {
        uint32_t u = *(const uint32_t*)&x[(size_t)row * C + c2 * 2];
        float a = bflo(u), b = bfhi(u);
        s0 += a; q0 += a * a; s1 += b; q1 += b * b;
    }
    float vals[4] = {s0, s1, q0, q1};
    float outv[4];
#pragma unroll
    for (int k = 0; k < 4; ++k) {
        red[t] = vals[k]; __syncthreads();
        if (rs == 0) {
            float s = red[c2];
#pragma unroll
            for (int r = 1; r < RPB; ++r) s += red[c2 + r * C2];
            outv[k] = s;
        }
        __syncthreads();
    }
    if (rs == 0) {
        atomicAdd(&sums[c2 * 2],     outv[0]);
        atomicAdd(&sums[c2 * 2 + 1], outv[1]);
        atomicAdd(&sums[C + c2 * 2],     outv[2]);
        atomicAdd(&sums[C + c2 * 2 + 1], outv[3]);
    }
}

template <int C, bool F32OUT>
__global__ __launch_bounds__(256) void bn_apply_elu2(const ushort* __restrict__ x, int n,
                                                     const float* __restrict__ g,
                                                     const float* __restrict__ be,
                                                     const float* __restrict__ sums,
                                                     ushort* __restrict__ outb,
                                                     float* __restrict__ outf) {
    int total = n * C / 8;
    float invn = 1.f / (float)n;
    for (int i = blockIdx.x * blockDim.x + threadIdx.x; i < total; i += gridDim.x * blockDim.x) {
        uint4 u = ((const uint4*)x)[i];
        int c0 = (i * 8) & (C - 1);
        float r[8] = {bflo(u.x), bfhi(u.x), bflo(u.y), bfhi(u.y),
                      bflo(u.z), bfhi(u.z), bflo(u.w), bfhi(u.w)};
#pragma unroll
        for (int j = 0; j < 8; ++j) {
            int c = c0 + j;
            float mu = sums[c] * invn;
            float var = sums[C + c] * invn - mu * mu;
            float t = g[c] * (r[j] - mu) * rsqrtf(var + 1e-5f) + be[c];
            r[j] = t > 0.f ? t : expm1f(t);
        }
        if constexpr (F32OUT) {
            ((float4*)outf)[i * 2]     = make_float4(r[0], r[1], r[2], r[3]);
            ((float4*)outf)[i * 2 + 1] = make_float4(r[4], r[5], r[6], r[7]);
        } else {
            uint4 o;
            o.x = (uint32_t)f2bf(r[0]) | ((uint32_t)f2bf(r[1]) << 16);
            o.y = (uint32_t)f2bf(r[2]) | ((uint32_t)f2bf(r[3]) << 16);
            o.z = (uint32_t)f2bf(r[4]) | ((uint32_t)f2bf(r[5]) << 16);
            o.w = (uint32_t)f2bf(r[6]) | ((uint32_t)f2bf(r[7]) << 16);
            ((uint4*)outb)[i] = o;
        }
    }
}

// ---------------------------------------------------------------- launch
extern "C" void kernel_launch(void* const* d_in, const int* in_sizes, int n_in,
                              void* d_out, int out_size, void* d_ws, size_t ws_size,
                              hipStream_t stream) {
    const float* emb = (const float*)d_in[0];
    const float* ew  = (const float*)d_in[1];
    const float* Wl0 = (const float*)d_in[2];
    const float* bl0 = (const float*)d_in[3];
    const float* Wr0 = (const float*)d_in[4];
    const float* br0 = (const float*)d_in[5];
    const float* We0 = (const float*)d_in[6];
    const float* att0 = (const float*)d_in[7];
    const float* b0  = (const float*)d_in[8];
    const float* g0  = (const float*)d_in[9];
    const float* be0 = (const float*)d_in[10];
    const float* Wl1 = (const float*)d_in[11];
    const float* bl1 = (const float*)d_in[12];
    const float* Wr1 = (const float*)d_in[13];
    const float* br1 = (const float*)d_in[14];
    const float* We1 = (const float*)d_in[15];
    const float* att1 = (const float*)d_in[16];
    const float* b1  = (const float*)d_in[17];
    const float* g1  = (const float*)d_in[18];
    const float* be1 = (const float*)d_in[19];
    const int* ei    = (const int*)d_in[20];

    const int N = in_sizes[0] / 128;
    const int E = in_sizes[1];
    const int Et = E + N;
    float* out = (float*)d_out;

    char* w = (char*)d_ws;
    size_t off = 0;
    auto alloc = [&](size_t bytes) {
        void* p = w + off;
        off = (off + bytes + 255) & ~(size_t)255;
        return p;
    };
    ushort* xlb    = (ushort*)alloc((size_t)N * 256 * 2);
    ushort* xrb    = (ushort*)alloc((size_t)N * 256 * 2);
    ushort* h0b16  = (ushort*)alloc((size_t)N * 128 * 2);   // gat0 out, in-place post-BN
    ushort* out16  = (ushort*)alloc((size_t)N * 64 * 2);    // gat1 out (pre-BN)
    ushort* embb   = (ushort*)alloc((size_t)N * 128 * 2);
    ushort* WT0    = (ushort*)alloc((size_t)256 * 128 * 2);
    ushort* WT1    = (ushort*)alloc((size_t)512 * 128 * 2);
    int*   deg     = (int*)alloc((size_t)2 * N * 4);        // deg + cursor (one memset)
    int*   cursor  = deg + N;
    int*   row_st  = (int*)alloc((size_t)(N + 1) * 4);
    int*   csr_src = (int*)alloc((size_t)Et * 4);
    float* csr_ea  = (float*)alloc((size_t)Et * 4);
    int*   bsum    = (int*)alloc(256 * 4);
    int*   boff    = (int*)alloc(256 * 4);
    float* partials= (float*)alloc(256 * 4);
    float* stats   = (float*)alloc(512 * 4);                // ew_mean + bn0 + bn1 (one memset)
    float* ew_mean = stats;
    float* bn0     = stats + 64;
    float* bn1     = stats + 64 + 256;
    (void)ws_size; (void)n_in; (void)out_size;

    hipMemsetAsync(deg, 0, (size_t)2 * N * 4, stream);
    hipMemsetAsync(stats, 0, 512 * 4, stream);

    // CSR build + prep
    degree_kernel<<<(Et + 255) / 256, 256, 0, stream>>>(ei, deg, E, N);
    ew_partial_kernel<<<256, 256, 0, stream>>>(ew, E, partials);
    const int NB1 = (N + 1023) / 1024;
    scan_partial<<<NB1, 256, 0, stream>>>(deg, N, bsum);
    scan_block<<<1, 256, 0, stream>>>(bsum, NB1, boff, row_st, N, Et, partials, E, ew_mean);
    scan_final<<<NB1, 256, 0, stream>>>(deg, N, boff, row_st);
    scatter_kernel<<<(Et + 255) / 256, 256, 0, stream>>>(ei, ew, ew_mean, row_st, cursor,
                                                         csr_src, csr_ea, E, N);
    const int n4 = N * 128 / 4;
    const int prep_total = n4 + 128 * 256 + 128 * 512;
    prep_kernel<<<(prep_total + 255) / 256, 256, 0, stream>>>(emb, embb, n4,
                                                              Wl0, Wr0, WT0, Wl1, Wr1, WT1);

    const int ntiles = (N + 127) / 128;
    const int GR0 = ntiles < 128 ? ntiles : 128;
    const int GR1 = ntiles < 64 ? ntiles : 64;

    // ---- layer 0
    mfma_linear2<<<dim3(2, GR0), 512, 0, stream>>>(embb, WT0, bl0, br0, xlb, xrb, N, 128);
    gat_agg<1, 128><<<(N + 3) / 4, 256, 0, stream>>>(xlb, xrb, row_st, csr_src, csr_ea,
                                                     We0, att0, b0, h0b16, N);
    bn_stats_bf16<128><<<128, 256, 0, stream>>>(h0b16, N, bn0);
    bn_apply_elu2<128, false><<<1024, 256, 0, stream>>>(h0b16, N, g0, be0, bn0, h0b16, nullptr);

    // ---- layer 1
    mfma_linear2<<<dim3(4, GR1), 512, 0, stream>>>(h0b16, WT1, bl1, br1, xlb, xrb, N, 256);
    gat_agg<4, 64><<<(N + 3) / 4, 256, 0, stream>>>(xlb, xrb, row_st, csr_src, csr_ea,
                                                    We1, att1, b1, out16, N);
    bn_stats_bf16<64><<<128, 256, 0, stream>>>(out16, N, bn1);
    bn_apply_elu2<64, true><<<1024, 256, 0, stream>>>(out16, N, g1, be1, bn1, nullptr, out);
}

// Round 6
// 321.756 us; speedup vs baseline: 1.5003x; 1.1652x over previous
//
#include <hip/hip_runtime.h>
#include <cstdint>
#include <cstddef>
#include <type_traits>

using f32x4 = __attribute__((ext_vector_type(4))) float;
using s16x8 = __attribute__((ext_vector_type(8))) short;

__device__ __forceinline__ ushort f2bf(float x) {
    uint32_t u = __builtin_bit_cast(uint32_t, x);
    u += 0x7fffu + ((u >> 16) & 1u);          // round-to-nearest-even
    return (ushort)(u >> 16);
}
__device__ __forceinline__ float bflo(uint32_t u) { return __builtin_bit_cast(float, u << 16); }
__device__ __forceinline__ float bfhi(uint32_t u) { return __builtin_bit_cast(float, u & 0xffff0000u); }

__device__ __forceinline__ void dec8(uint4 g, float* x) {
    x[0] = bflo(g.x); x[1] = bfhi(g.x); x[2] = bflo(g.y); x[3] = bfhi(g.y);
    x[4] = bflo(g.z); x[5] = bfhi(g.z); x[6] = bflo(g.w); x[7] = bfhi(g.w);
}

#define GLOAD_LDS16(g, l)                                                                  \
    __builtin_amdgcn_global_load_lds((const __attribute__((address_space(1))) void*)(g),  \
                                     (__attribute__((address_space(3))) void*)(l), 16, 0, 0)

// ---------------------------------------------------------------- CSR build
__global__ void degree_kernel(const int* __restrict__ ei, int* __restrict__ deg, int E, int N) {
    int e = blockIdx.x * blockDim.x + threadIdx.x;
    if (e >= E + N) return;
    int d = (e < E) ? ei[E + e] : (e - E);
    atomicAdd(&deg[d], 1);
}

// edge-weight partial sums: NO same-address atomics (plain store per block)
__global__ __launch_bounds__(256) void ew_partial_kernel(const float* __restrict__ ew, int E,
                                                          float* __restrict__ partials) {
    __shared__ float red[256];
    int t = threadIdx.x;
    float s = 0.f;
    int E4 = E >> 2;
    for (int i = blockIdx.x * 256 + t; i < E4; i += 256 * gridDim.x) {
        float4 v = ((const float4*)ew)[i];
        s += (v.x + v.y) + (v.z + v.w);
    }
    if (blockIdx.x == 0 && t < (E & 3)) s += ew[E4 * 4 + t];
    red[t] = s; __syncthreads();
    for (int o = 128; o; o >>= 1) { if (t < o) red[t] += red[t + o]; __syncthreads(); }
    if (t == 0) partials[blockIdx.x] = red[0];
}

__global__ void scan_partial(const int* __restrict__ deg, int n, int* __restrict__ bsum) {
    __shared__ int lds[256];
    int t = threadIdx.x;
    int base = blockIdx.x * 1024 + t * 4;
    int s = 0;
#pragma unroll
    for (int j = 0; j < 4; ++j) if (base + j < n) s += deg[base + j];
    lds[t] = s; __syncthreads();
    for (int o = 128; o; o >>= 1) { if (t < o) lds[t] += lds[t + o]; __syncthreads(); }
    if (t == 0) bsum[blockIdx.x] = lds[0];
}

// single block: scan of block sums + final ew mean
__global__ void scan_block(const int* __restrict__ bsum, int nb, int* __restrict__ boff,
                           int* __restrict__ row_start, int n, int total,
                           const float* __restrict__ partials, int E, float* __restrict__ ew_mean) {
    __shared__ int lds[256];
    __shared__ float fred[256];
    int t = threadIdx.x;
    int v = (t < nb) ? bsum[t] : 0;
    lds[t] = v; __syncthreads();
    for (int o = 1; o < 256; o <<= 1) {
        int y = (t >= o) ? lds[t - o] : 0;
        __syncthreads();
        lds[t] += y;
        __syncthreads();
    }
    if (t < nb) boff[t] = lds[t] - v;   // exclusive
    if (t == 0) row_start[n] = total;
    // reduce ew partials
    fred[t] = partials[t]; __syncthreads();
    for (int o = 128; o; o >>= 1) { if (t < o) fred[t] += fred[t + o]; __syncthreads(); }
    if (t == 0) ew_mean[0] = fred[0] / (float)E;
}

__global__ void scan_final(const int* __restrict__ deg, int n, const int* __restrict__ boff,
                           int* __restrict__ row_start) {
    __shared__ int lds[256];
    int t = threadIdx.x;
    int base = blockIdx.x * 1024 + t * 4;
    int d[4], loc[4], s = 0;
#pragma unroll
    for (int j = 0; j < 4; ++j) d[j] = (base + j < n) ? deg[base + j] : 0;
#pragma unroll
    for (int j = 0; j < 4; ++j) { loc[j] = s; s += d[j]; }
    lds[t] = s; __syncthreads();
    for (int o = 1; o < 256; o <<= 1) {
        int y = (t >= o) ? lds[t - o] : 0;
        __syncthreads();
        lds[t] += y;
        __syncthreads();
    }
    int texcl = lds[t] - s + boff[blockIdx.x];
#pragma unroll
    for (int j = 0; j < 4; ++j) if (base + j < n) row_start[base + j] = texcl + loc[j];
}

__global__ void scatter_kernel(const int* __restrict__ ei, const float* __restrict__ ew,
                               const float* __restrict__ ew_mean, const int* __restrict__ row_start,
                               int* __restrict__ cursor, int* __restrict__ csr_src,
                               float* __restrict__ csr_ea, int E, int N) {
    int e = blockIdx.x * blockDim.x + threadIdx.x;
    if (e >= E + N) return;
    int s, d; float w;
    if (e < E) { s = ei[e]; d = ei[E + e]; w = ew[e]; }
    else       { s = d = e - E;            w = ew_mean[0]; }
    int pos = row_start[d] + atomicAdd(&cursor[d], 1);
    csr_src[pos] = s;
    csr_ea[pos] = w;
}

// ---------------------------------------------------------------- prep: emb->bf16 + WT builds
__global__ void prep_kernel(const float* __restrict__ emb, ushort* __restrict__ embb, int n4,
                            const float* __restrict__ Wl0, const float* __restrict__ Wr0,
                            ushort* __restrict__ WT0,
                            const float* __restrict__ Wl1, const float* __restrict__ Wr1,
                            ushort* __restrict__ WT1) {
    int i = blockIdx.x * 256 + threadIdx.x;
    if (i < n4) {
        float4 v = ((const float4*)emb)[i];
        ushort4 o;
        o.x = f2bf(v.x); o.y = f2bf(v.y); o.z = f2bf(v.z); o.w = f2bf(v.w);
        ((ushort4*)embb)[i] = o;
        return;
    }
    int j = i - n4;
    if (j < 128 * 256) {
        int k = j >> 8, c = j & 255;
        float v = (c < 128) ? Wl0[k * 128 + c] : Wr0[k * 128 + (c - 128)];
        WT0[(size_t)c * 128 + k] = f2bf(v);
        return;
    }
    j -= 128 * 256;
    if (j < 128 * 512) {
        int k = j >> 9, c = j & 511;
        float v = (c < 256) ? Wl1[k * 256 + c] : Wr1[k * 256 + (c - 256)];
        WT1[(size_t)c * 128 + k] = f2bf(v);
    }
}

// ---------------------------------------------------------------- persistent col-panel MFMA GEMM
__global__ __launch_bounds__(512) void mfma_linear2(const ushort* __restrict__ Xb,
                                                    const ushort* __restrict__ WT,
                                                    const float* __restrict__ bl,
                                                    const float* __restrict__ br,
                                                    ushort* __restrict__ xl,
                                                    ushort* __restrict__ xr,
                                                    int n, int HALF) {
    __shared__ ushort sB[128 * 128];
    __shared__ ushort sA[2][128 * 128];
    const int tid = threadIdx.x;
    const int c0 = blockIdx.x * 128;
    const int ntiles = (n + 127) >> 7;

    {
        const ushort* src = WT + (size_t)c0 * 128;
#pragma unroll
        for (int it = 0; it < 4; ++it) {
            int f = tid + it * 512;
            int row = f >> 4, ch = f & 15;
            const ushort* g = src + (size_t)row * 128 + ((ch ^ (row & 7)) << 3);
            ushort* lp = sB + (((size_t)it * 512 + (tid & ~63)) << 3);
            GLOAD_LDS16(g, lp);
        }
    }

    auto stageA = [&](ushort* dstLds, int rt) {
        int r0 = rt << 7;
#pragma unroll
        for (int it = 0; it < 4; ++it) {
            int f = tid + it * 512;
            int row = f >> 4, ch = f & 15;
            int gr = r0 + row; gr = gr < n ? gr : n - 1;
            const ushort* g = Xb + (size_t)gr * 128 + ((ch ^ (row & 7)) << 3);
            ushort* lp = dstLds + (((size_t)it * 512 + (tid & ~63)) << 3);
            GLOAD_LDS16(g, lp);
        }
    };

    const int w = tid >> 6, l = tid & 63, lr = l & 15, lg = l >> 4;
    const bool left = c0 < HALF;
    const float* bias = left ? bl : br;
    ushort* dst = left ? xl : xr;
    const int cb = left ? c0 : c0 - HALF;
    float bv[8];
#pragma unroll
    for (int tn = 0; tn < 8; ++tn) bv[tn] = bias[cb + tn * 16 + lr];

    int rt = blockIdx.y;
    stageA(sA[0], rt);
    __syncthreads();

    int cur = 0;
    const int arow = w * 16 + lr;
    while (true) {
        int nx = rt + gridDim.y;
        if (nx < ntiles) stageA(sA[cur ^ 1], nx);

        f32x4 acc[8] = {};
        const ushort* sAc = sA[cur];
#pragma unroll
        for (int kk = 0; kk < 4; ++kk) {
            int ach = (kk * 4 + lg) ^ (arow & 7);
            s16x8 a = *(const s16x8*)&sAc[arow * 128 + (ach << 3)];
#pragma unroll
            for (int tn = 0; tn < 8; ++tn) {
                int brow = tn * 16 + lr;
                int bch = (kk * 4 + lg) ^ (brow & 7);
                s16x8 b = *(const s16x8*)&sB[brow * 128 + (bch << 3)];
                acc[tn] = __builtin_amdgcn_mfma_f32_16x16x32_bf16(a, b, acc[tn], 0, 0, 0);
            }
        }
        int rbase = (rt << 7) + w * 16 + lg * 4;
#pragma unroll
        for (int tn = 0; tn < 8; ++tn) {
            int colh = cb + tn * 16 + lr;
#pragma unroll
            for (int r = 0; r < 4; ++r) {
                int row = rbase + r;
                if (row < n) dst[(size_t)row * HALF + colh] = f2bf(acc[tn][r] + bv[tn]);
            }
        }
        if (nx >= ntiles) break;
        __syncthreads();
        cur ^= 1; rt = nx;
    }
}

// ---------------------------------------------------------------- GATv2 aggregation (bf16 in/out)
// LPN lanes own one node => 64/LPN independent node chains per wave (4x/2x
// memory-level parallelism vs one-node-per-wave). VPL=8 cols/lane, 16B gathers.
// leaky(u).att computed as 0.6*(att.u) + 0.4*(att.|u|) -- abs is a free VOP3
// modifier, so 4 VALU ops/element instead of 6.
template <int H, int C, int LPN>
__global__ __launch_bounds__(256, 8) void gat_agg(const ushort* __restrict__ xl,
                                                  const ushort* __restrict__ xr,
                                                  const int* __restrict__ row_start,
                                                  const int* __restrict__ csr_src,
                                                  const float* __restrict__ csr_ea,
                                                  const float* __restrict__ We,
                                                  const float* __restrict__ att,
                                                  const float* __restrict__ bias,
                                                  ushort* __restrict__ out, int n) {
    constexpr int HC = H * C;
    constexpr int VPL = HC / LPN;        // values per lane (8)
    constexpr int REDW = LPN / H;        // lanes per head (softmax reduce width)
    constexpr int NPW = 64 / LPN;        // nodes per wave
    static_assert(VPL == 8, "");

    const int wid = threadIdx.x >> 6;
    const int lane = threadIdx.x & 63;
    const int sl = lane & (LPN - 1);     // sublane within node group
    const int sub = lane / LPN;          // node slot within wave
    const int v = (blockIdx.x * 4 + wid) * NPW + sub;
    const bool valid = v < n;
    const int vv = valid ? v : n - 1;

    const int base = sl * VPL;
    int e = row_start[vv];
    int e1 = valid ? row_start[vv + 1] : e;

    // 1-deep prefetch of first edge row
    uint4 gN = {}; float wN = 0.f;
    if (e < e1) {
        int s = csr_src[e];
        wN = csr_ea[e];
        gN = *(const uint4*)&xl[(size_t)s * HC + base];
    }

    float xrv[8], wE[8], attv[8];
    dec8(*(const uint4*)&xr[(size_t)vv * HC + base], xrv);
#pragma unroll
    for (int j = 0; j < 8; j += 4) {
        float4 a = *(const float4*)&We[base + j];
        wE[j] = a.x; wE[j + 1] = a.y; wE[j + 2] = a.z; wE[j + 3] = a.w;
        float4 b = *(const float4*)&att[base + j];
        attv[j] = b.x; attv[j + 1] = b.y; attv[j + 2] = b.z; attv[j + 3] = b.w;
    }

    float m = -__builtin_inff(), den = 0.f, acc[8];
#pragma unroll
    for (int j = 0; j < 8; ++j) acc[j] = 0.f;

    for (; e < e1; ++e) {
        uint4 g = gN; float w = wN;
        if (e + 1 < e1) {
            int s = csr_src[e + 1];
            wN = csr_ea[e + 1];
            gN = *(const uint4*)&xl[(size_t)s * HC + base];
        }
        float xf[8];
        dec8(g, xf);
        float t1 = 0.f, t2 = 0.f;
#pragma unroll
        for (int j = 0; j < 8; ++j) {
            float u = xf[j] + fmaf(w, wE[j], xrv[j]);
            t1 = fmaf(u, attv[j], t1);
            t2 = fmaf(__builtin_fabsf(u), attv[j], t2);
        }
        float p = fmaf(0.6f, t1, 0.4f * t2);
#pragma unroll
        for (int o = REDW >> 1; o; o >>= 1) p += __shfl_xor(p, o, 64);
        // single-exp online update; first edge: d=+inf -> sc=0, pe=1
        float d = p - m;
        bool up = d > 0.f;
        float t = __expf(up ? -d : d);
        float sc = up ? t : 1.f;
        float pe = up ? 1.f : t;
        m = up ? p : m;
        den = fmaf(den, sc, pe);
#pragma unroll
        for (int j = 0; j < 8; ++j) acc[j] = fmaf(acc[j], sc, pe * xf[j]);
    }

    float inv = 1.f / (den + 1e-16f);
#pragma unroll
    for (int j = 0; j < 8; ++j) acc[j] *= inv;

    if constexpr (H > 1) {               // mean over heads (within node group)
#pragma unroll
        for (int o = REDW; o < LPN; o <<= 1)
#pragma unroll
            for (int j = 0; j < 8; ++j) acc[j] += __shfl_xor(acc[j], o, 64);
#pragma unroll
        for (int j = 0; j < 8; ++j) acc[j] *= (1.f / (float)H);
    }

    if (valid && sl < C / VPL) {
        float bv[8];
#pragma unroll
        for (int j = 0; j < 8; j += 4) {
            float4 b = *(const float4*)&bias[sl * VPL + j];
            bv[j] = b.x; bv[j + 1] = b.y; bv[j + 2] = b.z; bv[j + 3] = b.w;
        }
        uint4 o;
        o.x = (uint32_t)f2bf(acc[0] + bv[0]) | ((uint32_t)f2bf(acc[1] + bv[1]) << 16);
        o.y = (uint32_t)f2bf(acc[2] + bv[2]) | ((uint32_t)f2bf(acc[3] + bv[3]) << 16);
        o.z = (uint32_t)f2bf(acc[4] + bv[4]) | ((uint32_t)f2bf(acc[5] + bv[5]) << 16);
        o.w = (uint32_t)f2bf(acc[6] + bv[6]) | ((uint32_t)f2bf(acc[7] + bv[7]) << 16);
        *(uint4*)&out[(size_t)v * C + sl * VPL] = o;
    }
}

// ---------------------------------------------------------------- batchnorm (bf16 in)
template <int C>
__global__ __launch_bounds__(256) void bn_stats_bf16(const ushort* __restrict__ x, int n,
                                                     float* __restrict__ sums) {
    constexpr int C2 = C / 2;
    constexpr int RPB = 256 / C2;
    __shared__ float red[256];
    int t = threadIdx.x;
    int c2 = t % C2, rs = t / C2;
    float s0 = 0.f, s1 = 0.f, q0 = 0.f, q1 = 0.f;
    for (int row = blockIdx.x * RPB + rs; row < n; row += gridDim.x * RPB) {
        uint32_t u = *(const uint32_t*)&x[(size_t)row * C + c2 * 2];
        float a = bflo(u), b = bfhi(u);
        s0 += a; q0 += a * a; s1 += b; q1 += b * b;
    }
    float vals[4] = {s0, s1, q0, q1};
    float outv[4];
#pragma unroll
    for (int k = 0; k < 4; ++k) {
        red[t] = vals[k]; __syncthreads();
        if (rs == 0) {
            float s = red[c2];
#pragma unroll
            for (int r = 1; r < RPB; ++r) s += red[c2 + r * C2];
            outv[k] = s;
        }
        __syncthreads();
    }
    if (rs == 0) {
        atomicAdd(&sums[c2 * 2],     outv[0]);
        atomicAdd(&sums[c2 * 2 + 1], outv[1]);
        atomicAdd(&sums[C + c2 * 2],     outv[2]);
        atomicAdd(&sums[C + c2 * 2 + 1], outv[3]);
    }
}

template <int C, bool F32OUT>
__global__ __launch_bounds__(256) void bn_apply_elu2(const ushort* __restrict__ x, int n,
                                                     const float* __restrict__ g,
                                                     const float* __restrict__ be,
                                                     const float* __restrict__ sums,
                                                     ushort* __restrict__ outb,
                                                     float* __restrict__ outf) {
    int total = n * C / 8;
    float invn = 1.f / (float)n;
    for (int i = blockIdx.x * blockDim.x + threadIdx.x; i < total; i += gridDim.x * blockDim.x) {
        uint4 u = ((const uint4*)x)[i];
        int c0 = (i * 8) & (C - 1);
        float r[8] = {bflo(u.x), bfhi(u.x), bflo(u.y), bfhi(u.y),
                      bflo(u.z), bfhi(u.z), bflo(u.w), bfhi(u.w)};
#pragma unroll
        for (int j = 0; j < 8; ++j) {
            int c = c0 + j;
            float mu = sums[c] * invn;
            float var = sums[C + c] * invn - mu * mu;
            float t = g[c] * (r[j] - mu) * rsqrtf(var + 1e-5f) + be[c];
            r[j] = t > 0.f ? t : expm1f(t);
        }
        if constexpr (F32OUT) {
            ((float4*)outf)[i * 2]     = make_float4(r[0], r[1], r[2], r[3]);
            ((float4*)outf)[i * 2 + 1] = make_float4(r[4], r[5], r[6], r[7]);
        } else {
            uint4 o;
            o.x = (uint32_t)f2bf(r[0]) | ((uint32_t)f2bf(r[1]) << 16);
            o.y = (uint32_t)f2bf(r[2]) | ((uint32_t)f2bf(r[3]) << 16);
            o.z = (uint32_t)f2bf(r[4]) | ((uint32_t)f2bf(r[5]) << 16);
            o.w = (uint32_t)f2bf(r[6]) | ((uint32_t)f2bf(r[7]) << 16);
            ((uint4*)outb)[i] = o;
        }
    }
}

// ---------------------------------------------------------------- launch
extern "C" void kernel_launch(void* const* d_in, const int* in_sizes, int n_in,
                              void* d_out, int out_size, void* d_ws, size_t ws_size,
                              hipStream_t stream) {
    const float* emb = (const float*)d_in[0];
    const float* ew  = (const float*)d_in[1];
    const float* Wl0 = (const float*)d_in[2];
    const float* bl0 = (const float*)d_in[3];
    const float* Wr0 = (const float*)d_in[4];
    const float* br0 = (const float*)d_in[5];
    const float* We0 = (const float*)d_in[6];
    const float* att0 = (const float*)d_in[7];
    const float* b0  = (const float*)d_in[8];
    const float* g0  = (const float*)d_in[9];
    const float* be0 = (const float*)d_in[10];
    const float* Wl1 = (const float*)d_in[11];
    const float* bl1 = (const float*)d_in[12];
    const float* Wr1 = (const float*)d_in[13];
    const float* br1 = (const float*)d_in[14];
    const float* We1 = (const float*)d_in[15];
    const float* att1 = (const float*)d_in[16];
    const float* b1  = (const float*)d_in[17];
    const float* g1  = (const float*)d_in[18];
    const float* be1 = (const float*)d_in[19];
    const int* ei    = (const int*)d_in[20];

    const int N = in_sizes[0] / 128;
    const int E = in_sizes[1];
    const int Et = E + N;
    float* out = (float*)d_out;

    char* w = (char*)d_ws;
    size_t off = 0;
    auto alloc = [&](size_t bytes) {
        void* p = w + off;
        off = (off + bytes + 255) & ~(size_t)255;
        return p;
    };
    ushort* xlb    = (ushort*)alloc((size_t)N * 256 * 2);
    ushort* xrb    = (ushort*)alloc((size_t)N * 256 * 2);
    ushort* h0b16  = (ushort*)alloc((size_t)N * 128 * 2);   // gat0 out, in-place post-BN
    ushort* out16  = (ushort*)alloc((size_t)N * 64 * 2);    // gat1 out (pre-BN)
    ushort* embb   = (ushort*)alloc((size_t)N * 128 * 2);
    ushort* WT0    = (ushort*)alloc((size_t)256 * 128 * 2);
    ushort* WT1    = (ushort*)alloc((size_t)512 * 128 * 2);
    int*   deg     = (int*)alloc((size_t)2 * N * 4);        // deg + cursor (one memset)
    int*   cursor  = deg + N;
    int*   row_st  = (int*)alloc((size_t)(N + 1) * 4);
    int*   csr_src = (int*)alloc((size_t)Et * 4);
    float* csr_ea  = (float*)alloc((size_t)Et * 4);
    int*   bsum    = (int*)alloc(256 * 4);
    int*   boff    = (int*)alloc(256 * 4);
    float* partials= (float*)alloc(256 * 4);
    float* stats   = (float*)alloc(512 * 4);                // ew_mean + bn0 + bn1 (one memset)
    float* ew_mean = stats;
    float* bn0     = stats + 64;
    float* bn1     = stats + 64 + 256;
    (void)ws_size; (void)n_in; (void)out_size;

    hipMemsetAsync(deg, 0, (size_t)2 * N * 4, stream);
    hipMemsetAsync(stats, 0, 512 * 4, stream);

    // CSR build + prep
    degree_kernel<<<(Et + 255) / 256, 256, 0, stream>>>(ei, deg, E, N);
    ew_partial_kernel<<<256, 256, 0, stream>>>(ew, E, partials);
    const int NB1 = (N + 1023) / 1024;
    scan_partial<<<NB1, 256, 0, stream>>>(deg, N, bsum);
    scan_block<<<1, 256, 0, stream>>>(bsum, NB1, boff, row_st, N, Et, partials, E, ew_mean);
    scan_final<<<NB1, 256, 0, stream>>>(deg, N, boff, row_st);
    scatter_kernel<<<(Et + 255) / 256, 256, 0, stream>>>(ei, ew, ew_mean, row_st, cursor,
                                                         csr_src, csr_ea, E, N);
    const int n4 = N * 128 / 4;
    const int prep_total = n4 + 128 * 256 + 128 * 512;
    prep_kernel<<<(prep_total + 255) / 256, 256, 0, stream>>>(emb, embb, n4,
                                                              Wl0, Wr0, WT0, Wl1, Wr1, WT1);

    const int ntiles = (N + 127) / 128;
    const int GR0 = ntiles < 128 ? ntiles : 128;
    const int GR1 = ntiles < 64 ? ntiles : 64;

    // ---- layer 0
    mfma_linear2<<<dim3(2, GR0), 512, 0, stream>>>(embb, WT0, bl0, br0, xlb, xrb, N, 128);
    gat_agg<1, 128, 16><<<(N + 15) / 16, 256, 0, stream>>>(xlb, xrb, row_st, csr_src, csr_ea,
                                                           We0, att0, b0, h0b16, N);
    bn_stats_bf16<128><<<128, 256, 0, stream>>>(h0b16, N, bn0);
    bn_apply_elu2<128, false><<<1024, 256, 0, stream>>>(h0b16, N, g0, be0, bn0, h0b16, nullptr);

    // ---- layer 1
    mfma_linear2<<<dim3(4, GR1), 512, 0, stream>>>(h0b16, WT1, bl1, br1, xlb, xrb, N, 256);
    gat_agg<4, 64, 32><<<(N + 7) / 8, 256, 0, stream>>>(xlb, xrb, row_st, csr_src, csr_ea,
                                                        We1, att1, b1, out16, N);
    bn_stats_bf16<64><<<128, 256, 0, stream>>>(out16, N, bn1);
    bn_apply_elu2<64, true><<<1024, 256, 0, stream>>>(out16, N, g1, be1, bn1, nullptr, out);
}